// Round 1
// baseline (206.344 us; speedup 1.0000x reference)
//
#include <hip/hip_runtime.h>
#include <math.h>

#define B_ 32
#define L_ 512
#define D_ 512
#define H_ 512

typedef unsigned short u16;
typedef _Float16 h16;
typedef h16 half8 __attribute__((ext_vector_type(8)));
typedef float f32x4 __attribute__((ext_vector_type(4)));

// chunk swizzle: 16B chunks within a 64B LDS row, XOR by (row>>1)&3.
#define SW(r, c) ((c) ^ (((r) >> 1) & 3))

typedef __attribute__((address_space(1))) void gvoid;
typedef __attribute__((address_space(3))) void svoid;
__device__ __forceinline__ void async_cp16(const void* g, void* l) {
    __builtin_amdgcn_global_load_lds((gvoid*)g, (svoid*)l, 16, 0, 0);
}

__device__ __forceinline__ u16 f2h(float x) {
    h16 h = (h16)x;
    u16 r;
    __builtin_memcpy(&r, &h, 2);
    return r;
}
__device__ __forceinline__ float h2f(u16 u) {
    h16 h;
    __builtin_memcpy(&h, &u, 2);
    return (float)h;
}
// tanh(x) = 1 - 2/(exp(2x)+1); exact at +-inf, err < 2e-6 vs libm
__device__ __forceinline__ float fast_tanh(float x) {
    return 1.0f - 2.0f / (__expf(2.0f * x) + 1.0f);
}

// XCD-aware decode (round-robin heuristic): 16 tiles of one z-slice on one XCD.
__device__ __forceinline__ void xcd_decode16(int n, int& z, int& tile) {
    int xcd = n & 7, w = n >> 3;
    z = xcd + 8 * (w >> 4);
    tile = w & 15;
}

// ---------------------------------------------------------------------------
// one dispatch: fp32->fp16 convert(+transpose) for I (z<32), J (32<=z<64),
// W (z==64, transposed only). z==64 blocks also zero the output buffer.
// ---------------------------------------------------------------------------
__global__ __launch_bounds__(256) void cvt_all(const float* __restrict__ I,
                                               const float* __restrict__ Jm,
                                               const float* __restrict__ W,
                                               u16* __restrict__ Ih, u16* __restrict__ IhT,
                                               u16* __restrict__ Jh, u16* __restrict__ JhT,
                                               u16* __restrict__ WT,
                                               float* __restrict__ out) {
    const int z = blockIdx.z;
    const float* src;
    u16* h;
    u16* hT;
    size_t base;
    if (z < 32) {
        src = I; h = Ih; hT = IhT; base = (size_t)z * 512 * 512;
    } else if (z < 64) {
        src = Jm; h = Jh; hT = JhT; base = (size_t)(z - 32) * 512 * 512;
    } else {
        src = W; h = nullptr; hT = WT; base = 0;
        out[(blockIdx.y * 8 + blockIdx.x) * 256 + threadIdx.x] = 0.0f;
    }
    const int r0 = blockIdx.y * 64, c0 = blockIdx.x * 64;
    __shared__ u16 t[64][66];
    const int tid = threadIdx.x;
    const int tr = tid >> 4, tc4 = (tid & 15) * 4;
#pragma unroll
    for (int rep = 0; rep < 4; ++rep) {
        int r = rep * 16 + tr;
        f32x4 v = *(const f32x4*)(src + base + (size_t)(r0 + r) * 512 + c0 + tc4);
        unsigned h0 = f2h(v[0]), h1 = f2h(v[1]), h2 = f2h(v[2]), h3 = f2h(v[3]);
        if (h)
            *(uint2*)(h + base + (size_t)(r0 + r) * 512 + c0 + tc4) =
                make_uint2(h0 | (h1 << 16), h2 | (h3 << 16));
        t[r][tc4] = (u16)h0; t[r][tc4 + 1] = (u16)h1;
        t[r][tc4 + 2] = (u16)h2; t[r][tc4 + 3] = (u16)h3;
    }
    __syncthreads();
#pragma unroll
    for (int rep = 0; rep < 4; ++rep) {
        int r = rep * 16 + tr;
        unsigned a = t[tc4][r], b = t[tc4 + 1][r], c = t[tc4 + 2][r], d = t[tc4 + 3][r];
        *(uint2*)(hT + base + (size_t)(c0 + r) * 512 + r0 + tc4) =
            make_uint2(a | (b << 16), c | (d << 16));
    }
}

// ---------------------------------------------------------------------------
// score: S = I.J^T fp16 MFMA. Epilogue writes P_un = fp16(exp(S - rtmax)),
// P_unT = fp16(exp(S - ctmax)), + group stat arrays [b][512][8].
// ---------------------------------------------------------------------------
__global__ __launch_bounds__(256, 2) void score_mfma(const u16* __restrict__ Ih,
                                                     const u16* __restrict__ Jh,
                                                     u16* __restrict__ P_un,
                                                     u16* __restrict__ P_unT,
                                                     float* __restrict__ rtmax,
                                                     float* __restrict__ rtsum,
                                                     float* __restrict__ ctmax,
                                                     float* __restrict__ ctsum) {
    int b, tile;
    xcd_decode16(blockIdx.x, b, tile);  // 512 blocks: 32 b x 16 tiles
    const int i0 = (tile >> 2) * 128, j0 = (tile & 3) * 128;
    __shared__ u16 Ah[128 * 32], Bh[128 * 32];
    const int tid = threadIdx.x;
    const int wave = tid >> 6, lane = tid & 63;
    const int wm = (wave >> 1) * 64, wn = (wave & 1) * 64;
    const int lr = lane & 15, q = lane >> 4;
    const size_t boff = (size_t)b * L_ * D_;
    const u16* Ibh = Ih + boff;
    const u16* Jbh = Jh + boff;

    f32x4 acc[4][4] = {};

    for (int k0 = 0; k0 < D_; k0 += 32) {
#pragma unroll
        for (int h = 0; h < 2; ++h) {
            int g = wave * 2 + h;
            int r = g * 16 + (lane >> 2);
            int cg = SW(r, lane & 3);
            async_cp16(Ibh + (size_t)(i0 + r) * D_ + k0 + cg * 8, (char*)Ah + g * 1024);
            async_cp16(Jbh + (size_t)(j0 + r) * D_ + k0 + cg * 8, (char*)Bh + g * 1024);
        }
        __syncthreads();
        half8 af[4], bf[4];
#pragma unroll
        for (int mi = 0; mi < 4; ++mi) {
            int r = wm + mi * 16 + lr;
            af[mi] = *(const half8*)&Ah[r * 32 + SW(r, q) * 8];
        }
#pragma unroll
        for (int ni = 0; ni < 4; ++ni) {
            int r = wn + ni * 16 + lr;
            bf[ni] = *(const half8*)&Bh[r * 32 + SW(r, q) * 8];
        }
#pragma unroll
        for (int mi = 0; mi < 4; ++mi)
#pragma unroll
            for (int ni = 0; ni < 4; ++ni)
                acc[mi][ni] = __builtin_amdgcn_mfma_f32_16x16x32_f16(af[mi], bf[ni], acc[mi][ni], 0, 0, 0);
        __syncthreads();
    }

    // ---- epilogue: group stats + P_un / P_unT ----
    float rm[4][4];
#pragma unroll
    for (int mi = 0; mi < 4; ++mi)
#pragma unroll
        for (int r4 = 0; r4 < 4; ++r4) {
            float t = fmaxf(fmaxf(acc[mi][0][r4], acc[mi][1][r4]),
                            fmaxf(acc[mi][2][r4], acc[mi][3][r4]));
#pragma unroll
            for (int off = 1; off < 16; off <<= 1) t = fmaxf(t, __shfl_xor(t, off));
            rm[mi][r4] = t;
        }
    float cm[4];
#pragma unroll
    for (int ni = 0; ni < 4; ++ni) {
        float u = -1e30f;
#pragma unroll
        for (int mi = 0; mi < 4; ++mi)
#pragma unroll
            for (int r4 = 0; r4 < 4; ++r4) u = fmaxf(u, acc[mi][ni][r4]);
        u = fmaxf(u, __shfl_xor(u, 16));
        u = fmaxf(u, __shfl_xor(u, 32));
        cm[ni] = u;
    }

    u16* Pu_b = P_un + (size_t)b * L_ * L_;
    u16* PuT_b = P_unT + (size_t)b * L_ * L_;
    float rs[4][4] = {};
    float cs[4] = {};
#pragma unroll
    for (int mi = 0; mi < 4; ++mi)
#pragma unroll
        for (int ni = 0; ni < 4; ++ni) {
            int i_base = i0 + wm + mi * 16 + q * 4;
            int j = j0 + wn + ni * 16 + lr;
            unsigned pc[4];
#pragma unroll
            for (int r4 = 0; r4 < 4; ++r4) {
                float er = __expf(acc[mi][ni][r4] - rm[mi][r4]);
                rs[mi][r4] += er;
                Pu_b[(size_t)(i_base + r4) * L_ + j] = f2h(er);
                float ec = __expf(acc[mi][ni][r4] - cm[ni]);
                cs[ni] += ec;
                pc[r4] = f2h(ec);
            }
            *(uint2*)&PuT_b[(size_t)j * L_ + i_base] =
                make_uint2(pc[0] | (pc[1] << 16), pc[2] | (pc[3] << 16));
        }

    const int gr = (j0 + wn) >> 6;
    const int gc = (i0 + wm) >> 6;
#pragma unroll
    for (int mi = 0; mi < 4; ++mi)
#pragma unroll
        for (int r4 = 0; r4 < 4; ++r4) {
            float s = rs[mi][r4];
#pragma unroll
            for (int off = 1; off < 16; off <<= 1) s += __shfl_xor(s, off);
            if (lr == 0) {
                int i = i0 + wm + mi * 16 + q * 4 + r4;
                rtmax[((size_t)b * L_ + i) * 8 + gr] = rm[mi][r4];
                rtsum[((size_t)b * L_ + i) * 8 + gr] = s;
            }
        }
#pragma unroll
    for (int ni = 0; ni < 4; ++ni) {
        float s = cs[ni];
        s += __shfl_xor(s, 16);
        s += __shfl_xor(s, 32);
        if (q == 0) {
            int j = j0 + wn + ni * 16 + lr;
            ctmax[((size_t)b * L_ + j) * 8 + gc] = cm[ni];
            ctsum[((size_t)b * L_ + j) * 8 + gc] = s;
        }
    }
}

// ---------------------------------------------------------------------------
// FUSED absdiff + agg. One block = 64 l-rows of one side (zz = side*32+b).
// Phase A: X[64 x 512] = |Oh - (sc*P).V| into LDS (XOR-swizzled rows).
// Phase B: Y = X.W, tanh+bias, reduce over l, atomicAdd into out.
// 512 threads = 8 waves, wave tile 32x128 (16 MFMA per K-step per wave).
// Double-buffered global_load_lds staging, ONE barrier per K-step
// (stage t+1 issued before compute t; syncthreads drains both counters).
// LDS: 2x36KB stage (32KB V/W rows + 4KB P rows) + 64KB Xs + sc = 138KB.
// ---------------------------------------------------------------------------
__global__ __launch_bounds__(512, 2) void absagg(
    const u16* __restrict__ P_un, const u16* __restrict__ P_unT,
    const float* __restrict__ rtmax, const float* __restrict__ rtsum,
    const float* __restrict__ ctmax, const float* __restrict__ ctsum,
    const u16* __restrict__ JhT, const u16* __restrict__ IhT,
    const u16* __restrict__ Ih, const u16* __restrict__ Jh,
    const u16* __restrict__ Wt, const float* __restrict__ bias,
    float* __restrict__ out) {
    // 512 blocks: 8 l-tiles of one zz stay on one XCD (P/Vt/Oh/W L2-resident).
    const int n = blockIdx.x;
    const int xcd = n & 7, w = n >> 3;
    const int zz = xcd + 8 * (w >> 3);
    const int tile = w & 7;
    const int side = zz >> 5, b = zz & 31;
    const int l0 = tile * 64;

    const u16* Pb = (side ? P_unT : P_un) + (size_t)b * L_ * L_;
    const float* tmax = (side ? ctmax : rtmax) + (size_t)b * L_ * 8;
    const float* tsum = (side ? ctsum : rtsum) + (size_t)b * L_ * 8;
    const u16* Vt = (side ? IhT : JhT) + (size_t)b * (size_t)D_ * L_;
    const u16* Oh = (side ? Jh : Ih) + (size_t)b * L_ * D_;

    __shared__ u16 stage[2][18432];  // [buf]: bytes 0..32767 = V/W rows, 32768..36863 = P rows
    __shared__ u16 Xs[64 * 512];     // row-major [l][d] fp16, byte ^= (l&7)<<4
    __shared__ float sc[8][64];      // per-row softmax combine scale, group-major

    const int tid = threadIdx.x;
    const int wave = tid >> 6, lane = tid & 63;
    const int lr = lane & 15, q = lane >> 4;
    const int wl = (wave >> 2) * 32;  // wave l-offset   {0,32}
    const int wc = (wave & 3) * 128;  // wave d/h-offset {0,128,256,384}

    // prologue: combine 8 group stats -> per-row scale table (rows l0..l0+63)
    if (tid < 64) {
        const float* tm = tmax + (size_t)(l0 + tid) * 8;
        const float* ts = tsum + (size_t)(l0 + tid) * 8;
        f32x4 m0 = *(const f32x4*)tm, m1 = *(const f32x4*)(tm + 4);
        f32x4 s0 = *(const f32x4*)ts, s1 = *(const f32x4*)(ts + 4);
        float m = fmaxf(fmaxf(fmaxf(m0[0], m0[1]), fmaxf(m0[2], m0[3])),
                        fmaxf(fmaxf(m1[0], m1[1]), fmaxf(m1[2], m1[3])));
        float e0 = __expf(m0[0] - m), e1 = __expf(m0[1] - m);
        float e2 = __expf(m0[2] - m), e3 = __expf(m0[3] - m);
        float e4 = __expf(m1[0] - m), e5 = __expf(m1[1] - m);
        float e6 = __expf(m1[2] - m), e7 = __expf(m1[3] - m);
        float inv = 1.0f / (e0 * s0[0] + e1 * s0[1] + e2 * s0[2] + e3 * s0[3] +
                            e4 * s1[0] + e5 * s1[1] + e6 * s1[2] + e7 * s1[3]);
        sc[0][tid] = e0 * inv; sc[1][tid] = e1 * inv;
        sc[2][tid] = e2 * inv; sc[3][tid] = e3 * inv;
        sc[4][tid] = e4 * inv; sc[5][tid] = e5 * inv;
        sc[6][tid] = e6 * inv; sc[7][tid] = e7 * inv;
    }

    // stage for phase A: Ps = P rows l0..l0+63 (waves 0-3), Vs = Vt rows 0..511 (all waves)
    auto stageA = [&](int t, int bufi) {
        const int k0 = t * 32;
        char* buf = (char*)&stage[bufi][0];
        if (wave < 4) {
            int r = wave * 16 + (lane >> 2);
            int cg = SW(r, lane & 3);
            async_cp16(Pb + (size_t)(l0 + r) * L_ + k0 + cg * 8, buf + 32768 + wave * 1024);
        }
#pragma unroll
        for (int i = 0; i < 4; ++i) {
            int c = wave * 4 + i;
            int dR = c * 16 + (lane >> 2);
            int cg = SW(dR, lane & 3);
            async_cp16(Vt + (size_t)dR * L_ + k0 + cg * 8, buf + c * 1024);
        }
    };
    // stage for phase B: Ws = Wt rows 0..511 (all waves)
    auto stageB = [&](int t, int bufi) {
        const int k0 = t * 32;
        char* buf = (char*)&stage[bufi][0];
#pragma unroll
        for (int i = 0; i < 4; ++i) {
            int c = wave * 4 + i;
            int hR = c * 16 + (lane >> 2);
            int cg = SW(hR, lane & 3);
            async_cp16(Wt + (size_t)hR * D_ + k0 + cg * 8, buf + c * 1024);
        }
    };

    f32x4 acc[2][8] = {};

    // ---- phase A: X = |Oh - (sc*P).V| ----
    stageA(0, 0);
    __syncthreads();
#pragma unroll 2
    for (int t = 0; t < 16; ++t) {
        if (t < 15) stageA(t + 1, (t + 1) & 1);
        const u16* buf = &stage[t & 1][0];
        const int gk = t >> 1;
        half8 af[2], bf[8];
#pragma unroll
        for (int mi = 0; mi < 2; ++mi) {
            int r = wl + mi * 16 + lr;
            h16 s = (h16)sc[gk][r];
            half8 s8 = {s, s, s, s, s, s, s, s};
            af[mi] = *(const half8*)&buf[16384 + r * 32 + SW(r, q) * 8] * s8;
        }
#pragma unroll
        for (int ni = 0; ni < 8; ++ni) {
            int dR = wc + ni * 16 + lr;
            bf[ni] = *(const half8*)&buf[dR * 32 + SW(dR, q) * 8];
        }
#pragma unroll
        for (int mi = 0; mi < 2; ++mi)
#pragma unroll
            for (int ni = 0; ni < 8; ++ni)
                acc[mi][ni] = __builtin_amdgcn_mfma_f32_16x16x32_f16(af[mi], bf[ni], acc[mi][ni], 0, 0, 0);
        if (t < 15) __syncthreads();
    }

    // phase A epilogue: abs-diff vs Oh, write Xs (swizzled), re-zero acc
    const f32x4 vzero = {0.f, 0.f, 0.f, 0.f};
#pragma unroll
    for (int mi = 0; mi < 2; ++mi)
#pragma unroll
        for (int ni = 0; ni < 8; ++ni) {
            const int ll = wl + mi * 16 + q * 4;
            const int d = wc + ni * 16 + lr;
#pragma unroll
            for (int r4 = 0; r4 < 4; ++r4) {
                const int l = ll + r4;
                float x = fabsf(h2f(Oh[(size_t)(l0 + l) * D_ + d]) - acc[mi][ni][r4]);
                *(u16*)((char*)Xs + (((l * 512 + d) * 2) ^ ((l & 7) << 4))) = f2h(x);
            }
            acc[mi][ni] = vzero;
        }

    stageB(0, 0);  // buf0 last read at t=14 (all waves past that barrier) -> safe
    __syncthreads();  // Xs writes visible + Ws(0) staged

    // ---- phase B: Y = X.W ----
#pragma unroll 2
    for (int t = 0; t < 16; ++t) {
        if (t < 15) stageB(t + 1, (t + 1) & 1);
        const u16* buf = &stage[t & 1][0];
        const int k0 = t * 32;
        half8 af[2], bf[8];
#pragma unroll
        for (int mi = 0; mi < 2; ++mi) {
            int l = wl + mi * 16 + lr;
            af[mi] = *(const half8*)((const char*)Xs + ((l * 1024 + k0 * 2 + q * 16) ^ ((l & 7) << 4)));
        }
#pragma unroll
        for (int ni = 0; ni < 8; ++ni) {
            int hR = wc + ni * 16 + lr;
            bf[ni] = *(const half8*)&buf[hR * 32 + SW(hR, q) * 8];
        }
#pragma unroll
        for (int mi = 0; mi < 2; ++mi)
#pragma unroll
            for (int ni = 0; ni < 8; ++ni)
                acc[mi][ni] = __builtin_amdgcn_mfma_f32_16x16x32_f16(af[mi], bf[ni], acc[mi][ni], 0, 0, 0);
        if (t < 15) __syncthreads();
    }

    // phase B epilogue: tanh + bias, reduce over the wave's 32 l-rows, atomicAdd
#pragma unroll
    for (int ni = 0; ni < 8; ++ni) {
        const int hcol = wc + ni * 16 + lr;
        const float bsv = bias[hcol];
        float ssum = 0.f;
#pragma unroll
        for (int mi = 0; mi < 2; ++mi)
#pragma unroll
            for (int r4 = 0; r4 < 4; ++r4)
                ssum += fast_tanh(acc[mi][ni][r4] + bsv);
        ssum += __shfl_xor(ssum, 16);
        ssum += __shfl_xor(ssum, 32);
        if (q == 0) atomicAdd(&out[b * H_ + hcol], ssum * (0.5f / (float)L_));
    }
}

extern "C" void kernel_launch(void* const* d_in, const int* in_sizes, int n_in,
                              void* d_out, int out_size, void* d_ws, size_t ws_size,
                              hipStream_t stream) {
    const float* I = (const float*)d_in[0];
    const float* Jm = (const float*)d_in[1];
    const float* W = (const float*)d_in[2];
    const float* bias = (const float*)d_in[3];
    float* out = (float*)d_out;

    const size_t BLD = (size_t)B_ * L_ * D_;
    const size_t BLL = (size_t)B_ * L_ * L_;

    char* p = (char*)d_ws;
    auto give = [&](size_t bytes) {
        char* r = p;
        p += (bytes + 255) & ~(size_t)255;
        return r;
    };
    u16* Ih = (u16*)give(BLD * 2);
    u16* Jh = (u16*)give(BLD * 2);
    u16* IhT = (u16*)give(BLD * 2);
    u16* JhT = (u16*)give(BLD * 2);
    u16* WT = (u16*)give((size_t)D_ * H_ * 2);
    u16* P_un = (u16*)give(BLL * 2);
    u16* P_unT = (u16*)give(BLL * 2);
    float* rtmax = (float*)give((size_t)B_ * L_ * 8 * 4);
    float* rtsum = (float*)give((size_t)B_ * L_ * 8 * 4);
    float* ctmax = (float*)give((size_t)B_ * L_ * 8 * 4);
    float* ctsum = (float*)give((size_t)B_ * L_ * 8 * 4);

    cvt_all<<<dim3(8, 8, 65), 256, 0, stream>>>(I, Jm, W, Ih, IhT, Jh, JhT, WT, out);
    score_mfma<<<512, 256, 0, stream>>>(Ih, Jh, P_un, P_unT, rtmax, rtsum, ctmax, ctsum);
    absagg<<<512, 512, 0, stream>>>(P_un, P_unT, rtmax, rtsum, ctmax, ctsum,
                                    JhT, IhT, Ih, Jh, WT, bias, out);
}

// Round 2
// 195.708 us; speedup vs baseline: 1.0543x; 1.0543x over previous
//
#include <hip/hip_runtime.h>
#include <math.h>

#define B_ 32
#define L_ 512
#define D_ 512
#define H_ 512

typedef unsigned short u16;
typedef _Float16 h16;
typedef h16 half8 __attribute__((ext_vector_type(8)));
typedef float f32x4 __attribute__((ext_vector_type(4)));

// chunk swizzle: 16B chunks within a 64B LDS row, XOR by (row>>1)&3.
#define SW(r, c) ((c) ^ (((r) >> 1) & 3))

typedef __attribute__((address_space(1))) void gvoid;
typedef __attribute__((address_space(3))) void svoid;
__device__ __forceinline__ void async_cp16(const void* g, void* l) {
    __builtin_amdgcn_global_load_lds((gvoid*)g, (svoid*)l, 16, 0, 0);
}

__device__ __forceinline__ u16 f2h(float x) {
    h16 h = (h16)x;
    u16 r;
    __builtin_memcpy(&r, &h, 2);
    return r;
}
__device__ __forceinline__ float h2f(u16 u) {
    h16 h;
    __builtin_memcpy(&h, &u, 2);
    return (float)h;
}
// tanh(x) = 1 - 2/(exp(2x)+1); exact at +-inf, err < 2e-6 vs libm
__device__ __forceinline__ float fast_tanh(float x) {
    return 1.0f - 2.0f / (__expf(2.0f * x) + 1.0f);
}

// XCD-aware decode (round-robin heuristic): 16 tiles of one z-slice on one XCD.
__device__ __forceinline__ void xcd_decode16(int n, int& z, int& tile) {
    int xcd = n & 7, w = n >> 3;
    z = xcd + 8 * (w >> 4);
    tile = w & 15;
}

// ---------------------------------------------------------------------------
// one dispatch: fp32->fp16 convert(+transpose) for I (z<32), J (32<=z<64),
// W (z==64, transposed only). z==64 blocks also zero the output buffer.
// ---------------------------------------------------------------------------
__global__ __launch_bounds__(256) void cvt_all(const float* __restrict__ I,
                                               const float* __restrict__ Jm,
                                               const float* __restrict__ W,
                                               u16* __restrict__ Ih, u16* __restrict__ IhT,
                                               u16* __restrict__ Jh, u16* __restrict__ JhT,
                                               u16* __restrict__ WT,
                                               float* __restrict__ out) {
    const int z = blockIdx.z;
    const float* src;
    u16* h;
    u16* hT;
    size_t base;
    if (z < 32) {
        src = I; h = Ih; hT = IhT; base = (size_t)z * 512 * 512;
    } else if (z < 64) {
        src = Jm; h = Jh; hT = JhT; base = (size_t)(z - 32) * 512 * 512;
    } else {
        src = W; h = nullptr; hT = WT; base = 0;
        out[(blockIdx.y * 8 + blockIdx.x) * 256 + threadIdx.x] = 0.0f;
    }
    const int r0 = blockIdx.y * 64, c0 = blockIdx.x * 64;
    __shared__ u16 t[64][66];
    const int tid = threadIdx.x;
    const int tr = tid >> 4, tc4 = (tid & 15) * 4;
#pragma unroll
    for (int rep = 0; rep < 4; ++rep) {
        int r = rep * 16 + tr;
        f32x4 v = *(const f32x4*)(src + base + (size_t)(r0 + r) * 512 + c0 + tc4);
        unsigned h0 = f2h(v[0]), h1 = f2h(v[1]), h2 = f2h(v[2]), h3 = f2h(v[3]);
        if (h)
            *(uint2*)(h + base + (size_t)(r0 + r) * 512 + c0 + tc4) =
                make_uint2(h0 | (h1 << 16), h2 | (h3 << 16));
        t[r][tc4] = (u16)h0; t[r][tc4 + 1] = (u16)h1;
        t[r][tc4 + 2] = (u16)h2; t[r][tc4 + 3] = (u16)h3;
    }
    __syncthreads();
#pragma unroll
    for (int rep = 0; rep < 4; ++rep) {
        int r = rep * 16 + tr;
        unsigned a = t[tc4][r], b = t[tc4 + 1][r], c = t[tc4 + 2][r], d = t[tc4 + 3][r];
        *(uint2*)(hT + base + (size_t)(c0 + r) * 512 + r0 + tc4) =
            make_uint2(a | (b << 16), c | (d << 16));
    }
}

// ---------------------------------------------------------------------------
// score: S = I.J^T fp16 MFMA. Epilogue writes P_un = fp16(exp(S - rtmax)),
// P_unT = fp16(exp(S - ctmax)), + group stat arrays [b][512][8].
// ---------------------------------------------------------------------------
__global__ __launch_bounds__(256, 2) void score_mfma(const u16* __restrict__ Ih,
                                                     const u16* __restrict__ Jh,
                                                     u16* __restrict__ P_un,
                                                     u16* __restrict__ P_unT,
                                                     float* __restrict__ rtmax,
                                                     float* __restrict__ rtsum,
                                                     float* __restrict__ ctmax,
                                                     float* __restrict__ ctsum) {
    int b, tile;
    xcd_decode16(blockIdx.x, b, tile);  // 512 blocks: 32 b x 16 tiles
    const int i0 = (tile >> 2) * 128, j0 = (tile & 3) * 128;
    __shared__ u16 Ah[128 * 32], Bh[128 * 32];
    const int tid = threadIdx.x;
    const int wave = tid >> 6, lane = tid & 63;
    const int wm = (wave >> 1) * 64, wn = (wave & 1) * 64;
    const int lr = lane & 15, q = lane >> 4;
    const size_t boff = (size_t)b * L_ * D_;
    const u16* Ibh = Ih + boff;
    const u16* Jbh = Jh + boff;

    f32x4 acc[4][4] = {};

    for (int k0 = 0; k0 < D_; k0 += 32) {
#pragma unroll
        for (int h = 0; h < 2; ++h) {
            int g = wave * 2 + h;
            int r = g * 16 + (lane >> 2);
            int cg = SW(r, lane & 3);
            async_cp16(Ibh + (size_t)(i0 + r) * D_ + k0 + cg * 8, (char*)Ah + g * 1024);
            async_cp16(Jbh + (size_t)(j0 + r) * D_ + k0 + cg * 8, (char*)Bh + g * 1024);
        }
        __syncthreads();
        half8 af[4], bf[4];
#pragma unroll
        for (int mi = 0; mi < 4; ++mi) {
            int r = wm + mi * 16 + lr;
            af[mi] = *(const half8*)&Ah[r * 32 + SW(r, q) * 8];
        }
#pragma unroll
        for (int ni = 0; ni < 4; ++ni) {
            int r = wn + ni * 16 + lr;
            bf[ni] = *(const half8*)&Bh[r * 32 + SW(r, q) * 8];
        }
#pragma unroll
        for (int mi = 0; mi < 4; ++mi)
#pragma unroll
            for (int ni = 0; ni < 4; ++ni)
                acc[mi][ni] = __builtin_amdgcn_mfma_f32_16x16x32_f16(af[mi], bf[ni], acc[mi][ni], 0, 0, 0);
        __syncthreads();
    }

    // ---- epilogue: group stats + P_un / P_unT ----
    float rm[4][4];
#pragma unroll
    for (int mi = 0; mi < 4; ++mi)
#pragma unroll
        for (int r4 = 0; r4 < 4; ++r4) {
            float t = fmaxf(fmaxf(acc[mi][0][r4], acc[mi][1][r4]),
                            fmaxf(acc[mi][2][r4], acc[mi][3][r4]));
#pragma unroll
            for (int off = 1; off < 16; off <<= 1) t = fmaxf(t, __shfl_xor(t, off));
            rm[mi][r4] = t;
        }
    float cm[4];
#pragma unroll
    for (int ni = 0; ni < 4; ++ni) {
        float u = -1e30f;
#pragma unroll
        for (int mi = 0; mi < 4; ++mi)
#pragma unroll
            for (int r4 = 0; r4 < 4; ++r4) u = fmaxf(u, acc[mi][ni][r4]);
        u = fmaxf(u, __shfl_xor(u, 16));
        u = fmaxf(u, __shfl_xor(u, 32));
        cm[ni] = u;
    }

    u16* Pu_b = P_un + (size_t)b * L_ * L_;
    u16* PuT_b = P_unT + (size_t)b * L_ * L_;
    float rs[4][4] = {};
    float cs[4] = {};
#pragma unroll
    for (int mi = 0; mi < 4; ++mi)
#pragma unroll
        for (int ni = 0; ni < 4; ++ni) {
            int i_base = i0 + wm + mi * 16 + q * 4;
            int j = j0 + wn + ni * 16 + lr;
            unsigned pc[4];
#pragma unroll
            for (int r4 = 0; r4 < 4; ++r4) {
                float er = __expf(acc[mi][ni][r4] - rm[mi][r4]);
                rs[mi][r4] += er;
                Pu_b[(size_t)(i_base + r4) * L_ + j] = f2h(er);
                float ec = __expf(acc[mi][ni][r4] - cm[ni]);
                cs[ni] += ec;
                pc[r4] = f2h(ec);
            }
            *(uint2*)&PuT_b[(size_t)j * L_ + i_base] =
                make_uint2(pc[0] | (pc[1] << 16), pc[2] | (pc[3] << 16));
        }

    const int gr = (j0 + wn) >> 6;
    const int gc = (i0 + wm) >> 6;
#pragma unroll
    for (int mi = 0; mi < 4; ++mi)
#pragma unroll
        for (int r4 = 0; r4 < 4; ++r4) {
            float s = rs[mi][r4];
#pragma unroll
            for (int off = 1; off < 16; off <<= 1) s += __shfl_xor(s, off);
            if (lr == 0) {
                int i = i0 + wm + mi * 16 + q * 4 + r4;
                rtmax[((size_t)b * L_ + i) * 8 + gr] = rm[mi][r4];
                rtsum[((size_t)b * L_ + i) * 8 + gr] = s;
            }
        }
#pragma unroll
    for (int ni = 0; ni < 4; ++ni) {
        float s = cs[ni];
        s += __shfl_xor(s, 16);
        s += __shfl_xor(s, 32);
        if (q == 0) {
            int j = j0 + wn + ni * 16 + lr;
            ctmax[((size_t)b * L_ + j) * 8 + gc] = cm[ni];
            ctsum[((size_t)b * L_ + j) * 8 + gc] = s;
        }
    }
}

// ---------------------------------------------------------------------------
// X = | Oh - softmax . V | fp16, both sides (zz = side*32+b). 128x128 tiles.
// ---------------------------------------------------------------------------
__global__ __launch_bounds__(256, 2) void absdiff_scaled(const u16* __restrict__ P_un,
                                                         const u16* __restrict__ P_unT,
                                                         const float* __restrict__ rtmax,
                                                         const float* __restrict__ rtsum,
                                                         const float* __restrict__ ctmax,
                                                         const float* __restrict__ ctsum,
                                                         const u16* __restrict__ JhT,
                                                         const u16* __restrict__ IhT,
                                                         const u16* __restrict__ Ih,
                                                         const u16* __restrict__ Jh,
                                                         u16* __restrict__ Xall) {
    int zz, tile;
    xcd_decode16(blockIdx.x, zz, tile);  // 1024 blocks: 64 zz x 16 tiles
    const int side = zz >> 5, b = zz & 31;
    const int a0 = (tile >> 2) * 128, d0 = (tile & 3) * 128;
    const u16* Pb = (side ? P_unT : P_un) + (size_t)b * L_ * L_;
    const float* tmax = (side ? ctmax : rtmax) + (size_t)b * L_ * 8;
    const float* tsum = (side ? ctsum : rtsum) + (size_t)b * L_ * 8;
    const u16* Vt = (side ? IhT : JhT) + (size_t)b * D_ * L_;
    const u16* Oh = (side ? Jh : Ih) + (size_t)b * L_ * D_;
    u16* Xb = Xall + (size_t)zz * L_ * D_;

    __shared__ u16 As[128 * 32], Bs[128 * 32];
    __shared__ float sc[8][128];  // transposed: conflict-free gk-major reads
    const int tid = threadIdx.x;
    const int wave = tid >> 6, lane = tid & 63;
    const int wm = (wave >> 1) * 64, wn = (wave & 1) * 64;
    const int lr = lane & 15, q = lane >> 4;

    // prologue: combine 8 group stats -> per-row scale table
    if (tid < 128) {
        const float* tm = tmax + (size_t)(a0 + tid) * 8;
        const float* ts = tsum + (size_t)(a0 + tid) * 8;
        f32x4 m0 = *(const f32x4*)tm, m1 = *(const f32x4*)(tm + 4);
        f32x4 s0 = *(const f32x4*)ts, s1 = *(const f32x4*)(ts + 4);
        float m = fmaxf(fmaxf(fmaxf(m0[0], m0[1]), fmaxf(m0[2], m0[3])),
                        fmaxf(fmaxf(m1[0], m1[1]), fmaxf(m1[2], m1[3])));
        float e0 = __expf(m0[0] - m), e1 = __expf(m0[1] - m);
        float e2 = __expf(m0[2] - m), e3 = __expf(m0[3] - m);
        float e4 = __expf(m1[0] - m), e5 = __expf(m1[1] - m);
        float e6 = __expf(m1[2] - m), e7 = __expf(m1[3] - m);
        float inv = 1.0f / (e0 * s0[0] + e1 * s0[1] + e2 * s0[2] + e3 * s0[3] +
                            e4 * s1[0] + e5 * s1[1] + e6 * s1[2] + e7 * s1[3]);
        sc[0][tid] = e0 * inv; sc[1][tid] = e1 * inv;
        sc[2][tid] = e2 * inv; sc[3][tid] = e3 * inv;
        sc[4][tid] = e4 * inv; sc[5][tid] = e5 * inv;
        sc[6][tid] = e6 * inv; sc[7][tid] = e7 * inv;
    }
    __syncthreads();

    f32x4 acc[4][4] = {};

    for (int k0 = 0; k0 < L_; k0 += 32) {
#pragma unroll
        for (int h = 0; h < 2; ++h) {
            int g = wave * 2 + h;
            int r = g * 16 + (lane >> 2);
            int cg = SW(r, lane & 3);
            async_cp16(Pb + (size_t)(a0 + r) * L_ + k0 + cg * 8, (char*)As + g * 1024);
            async_cp16(Vt + (size_t)(d0 + r) * L_ + k0 + cg * 8, (char*)Bs + g * 1024);
        }
        __syncthreads();
        const int gk = k0 >> 6;
        half8 af[4], bf[4];
#pragma unroll
        for (int mi = 0; mi < 4; ++mi) {
            int r = wm + mi * 16 + lr;
            h16 s = (h16)sc[gk][r];
            half8 s8 = {s, s, s, s, s, s, s, s};
            af[mi] = *(const half8*)&As[r * 32 + SW(r, q) * 8] * s8;
        }
#pragma unroll
        for (int ni = 0; ni < 4; ++ni) {
            int r = wn + ni * 16 + lr;
            bf[ni] = *(const half8*)&Bs[r * 32 + SW(r, q) * 8];
        }
#pragma unroll
        for (int mi = 0; mi < 4; ++mi)
#pragma unroll
            for (int ni = 0; ni < 4; ++ni)
                acc[mi][ni] = __builtin_amdgcn_mfma_f32_16x16x32_f16(af[mi], bf[ni], acc[mi][ni], 0, 0, 0);
        __syncthreads();
    }

#pragma unroll
    for (int mi = 0; mi < 4; ++mi)
#pragma unroll
        for (int ni = 0; ni < 4; ++ni) {
            int i = a0 + wm + mi * 16 + q * 4;
            int d = d0 + wn + ni * 16 + lr;
#pragma unroll
            for (int r4 = 0; r4 < 4; ++r4) {
                float x = fabsf(h2f(Oh[(size_t)(i + r4) * D_ + d]) - acc[mi][ni][r4]);
                Xb[(size_t)(i + r4) * D_ + d] = f2h(x);
            }
        }
}

// ---------------------------------------------------------------------------
// agg, 8-phase 256x256-tile schedule (T3+T4+T5): out[b,h] += (0.5/L) *
// sum_l tanh( X[l,:].W[:,h] + bias[h] ).
// 256 blocks x 512 thr (8 waves, 2M x 4N; per-wave C = 128x64 = acc[8][4]).
// K=512 as 8 K-tiles of BK=64; each K-tile = 4 half-tiles (A/B x klo/khi),
// half-tile = 256 rows x 32 k fp16 = 16 KB (2 global_load_lds per wave).
// 2-K-tile LDS double buffer (128 KB). One half-tile staged per phase into
// the half freed one phase earlier; counted s_waitcnt vmcnt(4) at phases
// 4/8 only (each waited load issued >=3 phases earlier); raw s_barrier
// (never a vmcnt(0)-draining __syncthreads). XOR swizzle (r&3)<<4 applied
// on BOTH sides: inverse-swizzled global source (linear gload_lds dest) +
// swizzled ds_read addresses.
// ---------------------------------------------------------------------------
__global__ __launch_bounds__(512, 2) void agg_8ph(const u16* __restrict__ Xall,
                                                  const u16* __restrict__ Wt,
                                                  const float* __restrict__ bias,
                                                  float* __restrict__ out) {
    const int bid = blockIdx.x;  // 256 blocks: 8 XCD x (8 zz x 4 tiles)
    const int n = bid >> 3;
    const int zz = (bid & 7) + 8 * (n >> 2);
    const int tile = n & 3;
    const int bb = zz & 31;
    const int l0 = (tile >> 1) * 256, h0 = (tile & 1) * 256;
    const u16* Xb = Xall + (size_t)zz * L_ * D_ + (size_t)l0 * D_;
    const u16* Wb = Wt + (size_t)h0 * D_;

    __shared__ u16 AL[2][2][8192];  // [K-tile parity][k-half][256r x 32k]
    __shared__ u16 BL[2][2][8192];

    const int tid = threadIdx.x;
    const int wave = tid >> 6, lane = tid & 63;
    const int lr = lane & 15, q = lane >> 4;
    const int wr = wave >> 2, wc4 = wave & 3;

    // staging geometry: half-tile = 16 chunks of 1KB (16 rows x 64B); wave w
    // covers chunks 2w, 2w+1. LDS dest is linear (base + lane*16); source is
    // inverse-swizzled so that swizzled ds_reads see logical (r,k).
    const int ch0 = wave * 2;
    const int phys = lane * 16;
    const int Lb = phys ^ (((phys >> 6) & 3) << 4);  // involution on bits 4-5
    const int sr = Lb >> 6;          // row within chunk (0..15)
    const int sk = (Lb & 63) >> 1;   // k element offset {0,8,16,24}

#define ST_A(t, kh)                                                                     \
    do {                                                                                \
        char* dst_ = (char*)&AL[(t) & 1][(kh)][0];                                      \
        const u16* s_ = Xb + (t) * 64 + (kh) * 32 + sk;                                 \
        async_cp16(s_ + (size_t)(ch0 * 16 + sr) * D_, dst_ + ch0 * 1024);               \
        async_cp16(s_ + (size_t)(ch0 * 16 + 16 + sr) * D_, dst_ + ch0 * 1024 + 1024);   \
    } while (0)
#define ST_B(t, kh)                                                                     \
    do {                                                                                \
        char* dst_ = (char*)&BL[(t) & 1][(kh)][0];                                      \
        const u16* s_ = Wb + (t) * 64 + (kh) * 32 + sk;                                 \
        async_cp16(s_ + (size_t)(ch0 * 16 + sr) * D_, dst_ + ch0 * 1024);               \
        async_cp16(s_ + (size_t)(ch0 * 16 + 16 + sr) * D_, dst_ + ch0 * 1024 + 1024);   \
    } while (0)

    f32x4 acc[8][4] = {};

    // phase body: 8 swizzled ds_read_b128 + stage stmt + BAR + 16 MFMA + wait + BAR
#define PHASE(t, mh, kk, STAGE_STMT, WAIT_STMT)                                         \
    do {                                                                                \
        const char* Ah_ = (const char*)&AL[(t) & 1][(kk)][0];                           \
        const char* Bh_ = (const char*)&BL[(t) & 1][(kk)][0];                           \
        half8 a_[4], b_[4];                                                             \
        _Pragma("unroll") for (int mi = 0; mi < 4; ++mi) {                              \
            int r_ = wr * 128 + (mh)*64 + mi * 16 + lr;                                 \
            a_[mi] = *(const half8*)(Ah_ + r_ * 64 + ((q * 16) ^ ((r_ & 3) << 4)));     \
        }                                                                               \
        _Pragma("unroll") for (int ni = 0; ni < 4; ++ni) {                              \
            int r_ = wc4 * 64 + ni * 16 + lr;                                           \
            b_[ni] = *(const half8*)(Bh_ + r_ * 64 + ((q * 16) ^ ((r_ & 3) << 4)));     \
        }                                                                               \
        STAGE_STMT;                                                                     \
        asm volatile("" ::: "memory");                                                  \
        __builtin_amdgcn_s_barrier();                                                   \
        asm volatile("" ::: "memory");                                                  \
        __builtin_amdgcn_s_setprio(1);                                                  \
        _Pragma("unroll") for (int mi = 0; mi < 4; ++mi)                                \
            _Pragma("unroll") for (int ni = 0; ni < 4; ++ni)                            \
                acc[(mh)*4 + mi][ni] = __builtin_amdgcn_mfma_f32_16x16x32_f16(          \
                    a_[mi], b_[ni], acc[(mh)*4 + mi][ni], 0, 0, 0);                     \
        __builtin_amdgcn_s_setprio(0);                                                  \
        WAIT_STMT;                                                                      \
        asm volatile("" ::: "memory");                                                  \
        __builtin_amdgcn_s_barrier();                                                   \
        asm volatile("" ::: "memory");                                                  \
    } while (0)

#define VM4 asm volatile("s_waitcnt vmcnt(4)" ::: "memory")
#define VM0 asm volatile("s_waitcnt vmcnt(0)" ::: "memory")

    // prologue: T0 full (8 loads/wave) + T1 k0-halves (4) -> wait oldest 8
    ST_A(0, 0); ST_B(0, 0); ST_A(0, 1); ST_B(0, 1);
    ST_A(1, 0); ST_B(1, 0);
    VM4;
    asm volatile("" ::: "memory");
    __builtin_amdgcn_s_barrier();
    asm volatile("" ::: "memory");

    for (int it = 0; it < 4; ++it) {
        const int T = 2 * it, U = T + 1;
        const bool lastit = (it == 3);
        // ph1 [T,mh0,kk0]: stage U.A_k1 (parity U, freed 2 tiles ago)
        PHASE(T, 0, 0, { ST_A(U, 1); }, {});
        // ph2 [T,mh1,kk0]: stage U.B_k1
        PHASE(T, 1, 0, { ST_B(U, 1); }, {});
        // ph3 [T,mh0,kk1]: stage (T+2).A_k0 (T.A_k0 freed after ph2)
        PHASE(T, 0, 1, { if (!lastit) ST_A(T + 2, 0); }, {});
        // ph4 [T,mh1,kk1]: stage (T+2).B_k0; wait: all of U resident
        PHASE(T, 1, 1, { if (!lastit) ST_B(T + 2, 0); }, { if (lastit) VM0; else VM4; });
        // ph5 [U,mh0,kk0]: stage (T+2).A_k1 (T.A_k1 freed after ph4)
        PHASE(U, 0, 0, { if (!lastit) ST_A(T + 2, 1); }, {});
        // ph6 [U,mh1,kk0]: stage (T+2).B_k1
        PHASE(U, 1, 0, { if (!lastit) ST_B(T + 2, 1); }, {});
        // ph7 [U,mh0,kk1]: stage (T+3).A_k0 (U.A_k0 freed after ph6)
        PHASE(U, 0, 1, { if (!lastit) ST_A(T + 3, 0); }, {});
        // ph8 [U,mh1,kk1]: stage (T+3).B_k0; wait: all of T+2 resident
        PHASE(U, 1, 1, { if (!lastit) ST_B(T + 3, 0); }, { if (!lastit) VM4; });
    }

    // epilogue: tanh + bias, reduce the wave's 128 l-rows per h, atomicAdd
#pragma unroll
    for (int ni = 0; ni < 4; ++ni) {
        const int h = h0 + wc4 * 64 + ni * 16 + lr;
        const float bsv = bias[h];
        float ssum = 0.f;
#pragma unroll
        for (int mI = 0; mI < 8; ++mI)
#pragma unroll
            for (int r4 = 0; r4 < 4; ++r4)
                ssum += fast_tanh(acc[mI][ni][r4] + bsv);
        ssum += __shfl_xor(ssum, 16);
        ssum += __shfl_xor(ssum, 32);
        if (q == 0) atomicAdd(&out[bb * H_ + h], ssum * (0.5f / (float)L_));
    }
#undef PHASE
#undef ST_A
#undef ST_B
#undef VM4
#undef VM0
}

extern "C" void kernel_launch(void* const* d_in, const int* in_sizes, int n_in,
                              void* d_out, int out_size, void* d_ws, size_t ws_size,
                              hipStream_t stream) {
    const float* I = (const float*)d_in[0];
    const float* Jm = (const float*)d_in[1];
    const float* W = (const float*)d_in[2];
    const float* bias = (const float*)d_in[3];
    float* out = (float*)d_out;

    const size_t BLD = (size_t)B_ * L_ * D_;
    const size_t BLL = (size_t)B_ * L_ * L_;

    char* p = (char*)d_ws;
    auto give = [&](size_t bytes) {
        char* r = p;
        p += (bytes + 255) & ~(size_t)255;
        return r;
    };
    u16* Ih = (u16*)give(BLD * 2);
    u16* Jh = (u16*)give(BLD * 2);
    u16* IhT = (u16*)give(BLD * 2);
    u16* JhT = (u16*)give(BLD * 2);
    u16* WT = (u16*)give((size_t)D_ * H_ * 2);
    u16* P_un = (u16*)give(BLL * 2);
    u16* P_unT = (u16*)give(BLL * 2);
    float* rtmax = (float*)give((size_t)B_ * L_ * 8 * 4);
    float* rtsum = (float*)give((size_t)B_ * L_ * 8 * 4);
    float* ctmax = (float*)give((size_t)B_ * L_ * 8 * 4);
    float* ctsum = (float*)give((size_t)B_ * L_ * 8 * 4);
    u16* Xall = (u16*)give(2 * BLD * 2);

    cvt_all<<<dim3(8, 8, 65), 256, 0, stream>>>(I, Jm, W, Ih, IhT, Jh, JhT, WT, out);
    score_mfma<<<512, 256, 0, stream>>>(Ih, Jh, P_un, P_unT, rtmax, rtsum, ctmax, ctsum);
    absdiff_scaled<<<1024, 256, 0, stream>>>(P_un, P_unT, rtmax, rtsum, ctmax, ctsum,
                                             JhT, IhT, Ih, Jh, Xall);
    agg_8ph<<<256, 512, 0, stream>>>(Xall, WT, bias, out);
}

// Round 3
// 194.837 us; speedup vs baseline: 1.0591x; 1.0045x over previous
//
#include <hip/hip_runtime.h>
#include <math.h>

#define B_ 32
#define L_ 512
#define D_ 512
#define H_ 512

typedef unsigned short u16;
typedef _Float16 h16;
typedef h16 half8 __attribute__((ext_vector_type(8)));
typedef float f32x4 __attribute__((ext_vector_type(4)));

// chunk swizzle: 16B chunks within a 64B LDS row, XOR by (row>>1)&3.
#define SW(r, c) ((c) ^ (((r) >> 1) & 3))

typedef __attribute__((address_space(1))) void gvoid;
typedef __attribute__((address_space(3))) void svoid;
__device__ __forceinline__ void async_cp16(const void* g, void* l) {
    __builtin_amdgcn_global_load_lds((gvoid*)g, (svoid*)l, 16, 0, 0);
}

__device__ __forceinline__ u16 f2h(float x) {
    h16 h = (h16)x;
    u16 r;
    __builtin_memcpy(&r, &h, 2);
    return r;
}
__device__ __forceinline__ float h2f(u16 u) {
    h16 h;
    __builtin_memcpy(&h, &u, 2);
    return (float)h;
}
// tanh(x) = 1 - 2/(exp(2x)+1); exact at +-inf, err < 2e-6 vs libm
__device__ __forceinline__ float fast_tanh(float x) {
    return 1.0f - 2.0f / (__expf(2.0f * x) + 1.0f);
}

// XCD-aware decode (round-robin heuristic): 16 tiles of one z-slice on one XCD.
__device__ __forceinline__ void xcd_decode16(int n, int& z, int& tile) {
    int xcd = n & 7, w = n >> 3;
    z = xcd + 8 * (w >> 4);
    tile = w & 15;
}

// ---------------------------------------------------------------------------
// one dispatch: fp32->fp16 convert(+transpose) for I (z<32), J (32<=z<64),
// W (z==64, transposed only). z==64 blocks also zero the output buffer.
// ---------------------------------------------------------------------------
__global__ __launch_bounds__(256) void cvt_all(const float* __restrict__ I,
                                               const float* __restrict__ Jm,
                                               const float* __restrict__ W,
                                               u16* __restrict__ Ih, u16* __restrict__ IhT,
                                               u16* __restrict__ Jh, u16* __restrict__ JhT,
                                               u16* __restrict__ WT,
                                               float* __restrict__ out) {
    const int z = blockIdx.z;
    const float* src;
    u16* h;
    u16* hT;
    size_t base;
    if (z < 32) {
        src = I; h = Ih; hT = IhT; base = (size_t)z * 512 * 512;
    } else if (z < 64) {
        src = Jm; h = Jh; hT = JhT; base = (size_t)(z - 32) * 512 * 512;
    } else {
        src = W; h = nullptr; hT = WT; base = 0;
        out[(blockIdx.y * 8 + blockIdx.x) * 256 + threadIdx.x] = 0.0f;
    }
    const int r0 = blockIdx.y * 64, c0 = blockIdx.x * 64;
    __shared__ u16 t[64][66];
    const int tid = threadIdx.x;
    const int tr = tid >> 4, tc4 = (tid & 15) * 4;
#pragma unroll
    for (int rep = 0; rep < 4; ++rep) {
        int r = rep * 16 + tr;
        f32x4 v = *(const f32x4*)(src + base + (size_t)(r0 + r) * 512 + c0 + tc4);
        unsigned h0 = f2h(v[0]), h1 = f2h(v[1]), h2 = f2h(v[2]), h3 = f2h(v[3]);
        if (h)
            *(uint2*)(h + base + (size_t)(r0 + r) * 512 + c0 + tc4) =
                make_uint2(h0 | (h1 << 16), h2 | (h3 << 16));
        t[r][tc4] = (u16)h0; t[r][tc4 + 1] = (u16)h1;
        t[r][tc4 + 2] = (u16)h2; t[r][tc4 + 3] = (u16)h3;
    }
    __syncthreads();
#pragma unroll
    for (int rep = 0; rep < 4; ++rep) {
        int r = rep * 16 + tr;
        unsigned a = t[tc4][r], b = t[tc4 + 1][r], c = t[tc4 + 2][r], d = t[tc4 + 3][r];
        *(uint2*)(hT + base + (size_t)(c0 + r) * 512 + r0 + tc4) =
            make_uint2(a | (b << 16), c | (d << 16));
    }
}

// ---------------------------------------------------------------------------
// score: S = I.J^T fp16 MFMA. Epilogue writes P_un = fp16(exp(S - rtmax)),
// P_unT = fp16(exp(S - ctmax)), + group stat arrays [b][512][8].
// ---------------------------------------------------------------------------
__global__ __launch_bounds__(256, 2) void score_mfma(const u16* __restrict__ Ih,
                                                     const u16* __restrict__ Jh,
                                                     u16* __restrict__ P_un,
                                                     u16* __restrict__ P_unT,
                                                     float* __restrict__ rtmax,
                                                     float* __restrict__ rtsum,
                                                     float* __restrict__ ctmax,
                                                     float* __restrict__ ctsum) {
    int b, tile;
    xcd_decode16(blockIdx.x, b, tile);  // 512 blocks: 32 b x 16 tiles
    const int i0 = (tile >> 2) * 128, j0 = (tile & 3) * 128;
    __shared__ u16 Ah[128 * 32], Bh[128 * 32];
    const int tid = threadIdx.x;
    const int wave = tid >> 6, lane = tid & 63;
    const int wm = (wave >> 1) * 64, wn = (wave & 1) * 64;
    const int lr = lane & 15, q = lane >> 4;
    const size_t boff = (size_t)b * L_ * D_;
    const u16* Ibh = Ih + boff;
    const u16* Jbh = Jh + boff;

    f32x4 acc[4][4] = {};

    for (int k0 = 0; k0 < D_; k0 += 32) {
#pragma unroll
        for (int h = 0; h < 2; ++h) {
            int g = wave * 2 + h;
            int r = g * 16 + (lane >> 2);
            int cg = SW(r, lane & 3);
            async_cp16(Ibh + (size_t)(i0 + r) * D_ + k0 + cg * 8, (char*)Ah + g * 1024);
            async_cp16(Jbh + (size_t)(j0 + r) * D_ + k0 + cg * 8, (char*)Bh + g * 1024);
        }
        __syncthreads();
        half8 af[4], bf[4];
#pragma unroll
        for (int mi = 0; mi < 4; ++mi) {
            int r = wm + mi * 16 + lr;
            af[mi] = *(const half8*)&Ah[r * 32 + SW(r, q) * 8];
        }
#pragma unroll
        for (int ni = 0; ni < 4; ++ni) {
            int r = wn + ni * 16 + lr;
            bf[ni] = *(const half8*)&Bh[r * 32 + SW(r, q) * 8];
        }
#pragma unroll
        for (int mi = 0; mi < 4; ++mi)
#pragma unroll
            for (int ni = 0; ni < 4; ++ni)
                acc[mi][ni] = __builtin_amdgcn_mfma_f32_16x16x32_f16(af[mi], bf[ni], acc[mi][ni], 0, 0, 0);
        __syncthreads();
    }

    // ---- epilogue: group stats + P_un / P_unT ----
    float rm[4][4];
#pragma unroll
    for (int mi = 0; mi < 4; ++mi)
#pragma unroll
        for (int r4 = 0; r4 < 4; ++r4) {
            float t = fmaxf(fmaxf(acc[mi][0][r4], acc[mi][1][r4]),
                            fmaxf(acc[mi][2][r4], acc[mi][3][r4]));
#pragma unroll
            for (int off = 1; off < 16; off <<= 1) t = fmaxf(t, __shfl_xor(t, off));
            rm[mi][r4] = t;
        }
    float cm[4];
#pragma unroll
    for (int ni = 0; ni < 4; ++ni) {
        float u = -1e30f;
#pragma unroll
        for (int mi = 0; mi < 4; ++mi)
#pragma unroll
            for (int r4 = 0; r4 < 4; ++r4) u = fmaxf(u, acc[mi][ni][r4]);
        u = fmaxf(u, __shfl_xor(u, 16));
        u = fmaxf(u, __shfl_xor(u, 32));
        cm[ni] = u;
    }

    u16* Pu_b = P_un + (size_t)b * L_ * L_;
    u16* PuT_b = P_unT + (size_t)b * L_ * L_;
    float rs[4][4] = {};
    float cs[4] = {};
#pragma unroll
    for (int mi = 0; mi < 4; ++mi)
#pragma unroll
        for (int ni = 0; ni < 4; ++ni) {
            int i_base = i0 + wm + mi * 16 + q * 4;
            int j = j0 + wn + ni * 16 + lr;
            unsigned pc[4];
#pragma unroll
            for (int r4 = 0; r4 < 4; ++r4) {
                float er = __expf(acc[mi][ni][r4] - rm[mi][r4]);
                rs[mi][r4] += er;
                Pu_b[(size_t)(i_base + r4) * L_ + j] = f2h(er);
                float ec = __expf(acc[mi][ni][r4] - cm[ni]);
                cs[ni] += ec;
                pc[r4] = f2h(ec);
            }
            *(uint2*)&PuT_b[(size_t)j * L_ + i_base] =
                make_uint2(pc[0] | (pc[1] << 16), pc[2] | (pc[3] << 16));
        }

    const int gr = (j0 + wn) >> 6;
    const int gc = (i0 + wm) >> 6;
#pragma unroll
    for (int mi = 0; mi < 4; ++mi)
#pragma unroll
        for (int r4 = 0; r4 < 4; ++r4) {
            float s = rs[mi][r4];
#pragma unroll
            for (int off = 1; off < 16; off <<= 1) s += __shfl_xor(s, off);
            if (lr == 0) {
                int i = i0 + wm + mi * 16 + q * 4 + r4;
                rtmax[((size_t)b * L_ + i) * 8 + gr] = rm[mi][r4];
                rtsum[((size_t)b * L_ + i) * 8 + gr] = s;
            }
        }
#pragma unroll
    for (int ni = 0; ni < 4; ++ni) {
        float s = cs[ni];
        s += __shfl_xor(s, 16);
        s += __shfl_xor(s, 32);
        if (q == 0) {
            int j = j0 + wn + ni * 16 + lr;
            ctmax[((size_t)b * L_ + j) * 8 + gc] = cm[ni];
            ctsum[((size_t)b * L_ + j) * 8 + gc] = s;
        }
    }
}

// ---------------------------------------------------------------------------
// absdiff, 8-phase 256x256-tile schedule (T3+T4+T5), structural clone of
// agg_8ph: X = | Oh - softmax . V |, both sides (zz = side*32+b).
// 256 blocks x 512 thr (8 waves, 2M x 4N; per-wave C = 128l x 64d).
// Per-row softmax combine scale scl[8][256] f32 in LDS (K-tile index == the
// 64-wide k-group); A fragments scaled in fp16 exactly as before (same
// numerics / accumulation order). Counted vmcnt(4) at phases 4/8, raw
// s_barrier, both-sides XOR swizzle.
// LDS: 128 KB stage + 8 KB scl = 136 KB -> 1 block/CU, 2 waves/SIMD.
// ---------------------------------------------------------------------------
__global__ __launch_bounds__(512, 2) void absdiff_8ph(
    const u16* __restrict__ P_un, const u16* __restrict__ P_unT,
    const float* __restrict__ rtmax, const float* __restrict__ rtsum,
    const float* __restrict__ ctmax, const float* __restrict__ ctsum,
    const u16* __restrict__ JhT, const u16* __restrict__ IhT,
    const u16* __restrict__ Ih, const u16* __restrict__ Jh,
    u16* __restrict__ Xall) {
    const int bid = blockIdx.x;  // 256 blocks: 8 xcd x (8 zgrp x 4 tiles)
    const int n = bid >> 3;
    const int zz = (bid & 7) + 8 * (n >> 2);
    const int tile = n & 3;
    const int side = zz >> 5, b = zz & 31;
    const int l0 = (tile >> 1) * 256, d0 = (tile & 1) * 256;

    const u16* Pb = (side ? P_unT : P_un) + (size_t)b * L_ * L_ + (size_t)l0 * L_;
    const float* tmax = (side ? ctmax : rtmax) + (size_t)b * L_ * 8;
    const float* tsum = (side ? ctsum : rtsum) + (size_t)b * L_ * 8;
    const u16* Vtb = (side ? IhT : JhT) + (size_t)b * (size_t)D_ * L_ + (size_t)d0 * L_;
    const u16* Oh = (side ? Jh : Ih) + (size_t)b * L_ * D_;
    u16* Xb = Xall + (size_t)zz * L_ * D_;

    __shared__ u16 AL[2][2][8192];  // [K-tile parity][k-half][256r x 32k]
    __shared__ u16 BL[2][2][8192];
    __shared__ float scl[8][256];   // [k-group][row] combine scale

    const int tid = threadIdx.x;
    const int wave = tid >> 6, lane = tid & 63;
    const int lr = lane & 15, q = lane >> 4;
    const int wr = wave >> 2, wc4 = wave & 3;

    // prologue: combine 8 group stats -> per-row scale table (rows l0..l0+255)
    if (tid < 256) {
        const float* tm = tmax + (size_t)(l0 + tid) * 8;
        const float* ts = tsum + (size_t)(l0 + tid) * 8;
        f32x4 m0 = *(const f32x4*)tm, m1 = *(const f32x4*)(tm + 4);
        f32x4 s0 = *(const f32x4*)ts, s1 = *(const f32x4*)(ts + 4);
        float m = fmaxf(fmaxf(fmaxf(m0[0], m0[1]), fmaxf(m0[2], m0[3])),
                        fmaxf(fmaxf(m1[0], m1[1]), fmaxf(m1[2], m1[3])));
        float e0 = __expf(m0[0] - m), e1 = __expf(m0[1] - m);
        float e2 = __expf(m0[2] - m), e3 = __expf(m0[3] - m);
        float e4 = __expf(m1[0] - m), e5 = __expf(m1[1] - m);
        float e6 = __expf(m1[2] - m), e7 = __expf(m1[3] - m);
        float inv = 1.0f / (e0 * s0[0] + e1 * s0[1] + e2 * s0[2] + e3 * s0[3] +
                            e4 * s1[0] + e5 * s1[1] + e6 * s1[2] + e7 * s1[3]);
        scl[0][tid] = e0 * inv; scl[1][tid] = e1 * inv;
        scl[2][tid] = e2 * inv; scl[3][tid] = e3 * inv;
        scl[4][tid] = e4 * inv; scl[5][tid] = e5 * inv;
        scl[6][tid] = e6 * inv; scl[7][tid] = e7 * inv;
    }

    // staging geometry: half-tile = 16 chunks of 1KB (16 rows x 64B); wave w
    // covers chunks 2w, 2w+1. LDS dest linear; source inverse-swizzled.
    const int ch0 = wave * 2;
    const int phys = lane * 16;
    const int Lb = phys ^ (((phys >> 6) & 3) << 4);  // involution on bits 4-5
    const int sr = Lb >> 6;          // row within chunk (0..15)
    const int sk = (Lb & 63) >> 1;   // k element offset {0,8,16,24}

#define ST_A(t, kh)                                                                     \
    do {                                                                                \
        char* dst_ = (char*)&AL[(t) & 1][(kh)][0];                                      \
        const u16* s_ = Pb + (t) * 64 + (kh) * 32 + sk;                                 \
        async_cp16(s_ + (size_t)(ch0 * 16 + sr) * L_, dst_ + ch0 * 1024);               \
        async_cp16(s_ + (size_t)(ch0 * 16 + 16 + sr) * L_, dst_ + ch0 * 1024 + 1024);   \
    } while (0)
#define ST_B(t, kh)                                                                     \
    do {                                                                                \
        char* dst_ = (char*)&BL[(t) & 1][(kh)][0];                                      \
        const u16* s_ = Vtb + (t) * 64 + (kh) * 32 + sk;                                \
        async_cp16(s_ + (size_t)(ch0 * 16 + sr) * L_, dst_ + ch0 * 1024);               \
        async_cp16(s_ + (size_t)(ch0 * 16 + 16 + sr) * L_, dst_ + ch0 * 1024 + 1024);   \
    } while (0)

    f32x4 acc[8][4] = {};

#define PHASE(t, mh, kk, STAGE_STMT, WAIT_STMT)                                         \
    do {                                                                                \
        const char* Ah_ = (const char*)&AL[(t) & 1][(kk)][0];                           \
        const char* Bh_ = (const char*)&BL[(t) & 1][(kk)][0];                           \
        half8 a_[4], b_[4];                                                             \
        _Pragma("unroll") for (int mi = 0; mi < 4; ++mi) {                              \
            int r_ = wr * 128 + (mh)*64 + mi * 16 + lr;                                 \
            half8 av_ = *(const half8*)(Ah_ + r_ * 64 + ((q * 16) ^ ((r_ & 3) << 4)));  \
            h16 s_ = (h16)scl[(t)][r_];                                                 \
            half8 s8_ = {s_, s_, s_, s_, s_, s_, s_, s_};                               \
            a_[mi] = av_ * s8_;                                                         \
        }                                                                               \
        _Pragma("unroll") for (int ni = 0; ni < 4; ++ni) {                              \
            int r_ = wc4 * 64 + ni * 16 + lr;                                           \
            b_[ni] = *(const half8*)(Bh_ + r_ * 64 + ((q * 16) ^ ((r_ & 3) << 4)));     \
        }                                                                               \
        STAGE_STMT;                                                                     \
        asm volatile("" ::: "memory");                                                  \
        __builtin_amdgcn_s_barrier();                                                   \
        asm volatile("" ::: "memory");                                                  \
        __builtin_amdgcn_s_setprio(1);                                                  \
        _Pragma("unroll") for (int mi = 0; mi < 4; ++mi)                                \
            _Pragma("unroll") for (int ni = 0; ni < 4; ++ni)                            \
                acc[(mh)*4 + mi][ni] = __builtin_amdgcn_mfma_f32_16x16x32_f16(          \
                    a_[mi], b_[ni], acc[(mh)*4 + mi][ni], 0, 0, 0);                     \
        __builtin_amdgcn_s_setprio(0);                                                  \
        WAIT_STMT;                                                                      \
        asm volatile("" ::: "memory");                                                  \
        __builtin_amdgcn_s_barrier();                                                   \
        asm volatile("" ::: "memory");                                                  \
    } while (0)

#define VM4 asm volatile("s_waitcnt vmcnt(4)" ::: "memory")
#define VM0 asm volatile("s_waitcnt vmcnt(0)" ::: "memory")

    // prologue: T0 full + T1 k0-halves; drain scl ds_writes (lgkm) + oldest 8 vm
    ST_A(0, 0); ST_B(0, 0); ST_A(0, 1); ST_B(0, 1);
    ST_A(1, 0); ST_B(1, 0);
    asm volatile("s_waitcnt lgkmcnt(0)" ::: "memory");
    VM4;
    asm volatile("" ::: "memory");
    __builtin_amdgcn_s_barrier();
    asm volatile("" ::: "memory");

    for (int it = 0; it < 4; ++it) {
        const int T = 2 * it, U = T + 1;
        const bool lastit = (it == 3);
        PHASE(T, 0, 0, { ST_A(U, 1); }, {});
        PHASE(T, 1, 0, { ST_B(U, 1); }, {});
        PHASE(T, 0, 1, { if (!lastit) ST_A(T + 2, 0); }, {});
        PHASE(T, 1, 1, { if (!lastit) ST_B(T + 2, 0); }, { if (lastit) VM0; else VM4; });
        PHASE(U, 0, 0, { if (!lastit) ST_A(T + 2, 1); }, {});
        PHASE(U, 1, 0, { if (!lastit) ST_B(T + 2, 1); }, {});
        PHASE(U, 0, 1, { if (!lastit) ST_A(T + 3, 0); }, {});
        PHASE(U, 1, 1, { if (!lastit) ST_B(T + 3, 0); }, { if (!lastit) VM4; });
    }

    // epilogue: |Oh - acc| -> Xb (absolute l/d indices include l0/d0)
#pragma unroll
    for (int mh = 0; mh < 2; ++mh)
#pragma unroll
        for (int mi = 0; mi < 4; ++mi)
#pragma unroll
            for (int ni = 0; ni < 4; ++ni) {
                const int l_base = l0 + wr * 128 + mh * 64 + mi * 16 + q * 4;
                const int d = d0 + wc4 * 64 + ni * 16 + lr;
#pragma unroll
                for (int r4 = 0; r4 < 4; ++r4) {
                    float x = fabsf(h2f(Oh[(size_t)(l_base + r4) * D_ + d]) -
                                    acc[mh * 4 + mi][ni][r4]);
                    Xb[(size_t)(l_base + r4) * D_ + d] = f2h(x);
                }
            }
#undef PHASE
#undef ST_A
#undef ST_B
#undef VM4
#undef VM0
}

// ---------------------------------------------------------------------------
// agg, 8-phase 256x256-tile schedule (T3+T4+T5): out[b,h] += (0.5/L) *
// sum_l tanh( X[l,:].W[:,h] + bias[h] ).
// ---------------------------------------------------------------------------
__global__ __launch_bounds__(512, 2) void agg_8ph(const u16* __restrict__ Xall,
                                                  const u16* __restrict__ Wt,
                                                  const float* __restrict__ bias,
                                                  float* __restrict__ out) {
    const int bid = blockIdx.x;  // 256 blocks: 8 XCD x (8 zz x 4 tiles)
    const int n = bid >> 3;
    const int zz = (bid & 7) + 8 * (n >> 2);
    const int tile = n & 3;
    const int bb = zz & 31;
    const int l0 = (tile >> 1) * 256, h0 = (tile & 1) * 256;
    const u16* Xb = Xall + (size_t)zz * L_ * D_ + (size_t)l0 * D_;
    const u16* Wb = Wt + (size_t)h0 * D_;

    __shared__ u16 AL[2][2][8192];  // [K-tile parity][k-half][256r x 32k]
    __shared__ u16 BL[2][2][8192];

    const int tid = threadIdx.x;
    const int wave = tid >> 6, lane = tid & 63;
    const int lr = lane & 15, q = lane >> 4;
    const int wr = wave >> 2, wc4 = wave & 3;

    const int ch0 = wave * 2;
    const int phys = lane * 16;
    const int Lb = phys ^ (((phys >> 6) & 3) << 4);  // involution on bits 4-5
    const int sr = Lb >> 6;          // row within chunk (0..15)
    const int sk = (Lb & 63) >> 1;   // k element offset {0,8,16,24}

#define ST_A(t, kh)                                                                     \
    do {                                                                                \
        char* dst_ = (char*)&AL[(t) & 1][(kh)][0];                                      \
        const u16* s_ = Xb + (t) * 64 + (kh) * 32 + sk;                                 \
        async_cp16(s_ + (size_t)(ch0 * 16 + sr) * D_, dst_ + ch0 * 1024);               \
        async_cp16(s_ + (size_t)(ch0 * 16 + 16 + sr) * D_, dst_ + ch0 * 1024 + 1024);   \
    } while (0)
#define ST_B(t, kh)                                                                     \
    do {                                                                                \
        char* dst_ = (char*)&BL[(t) & 1][(kh)][0];                                      \
        const u16* s_ = Wb + (t) * 64 + (kh) * 32 + sk;                                 \
        async_cp16(s_ + (size_t)(ch0 * 16 + sr) * D_, dst_ + ch0 * 1024);               \
        async_cp16(s_ + (size_t)(ch0 * 16 + 16 + sr) * D_, dst_ + ch0 * 1024 + 1024);   \
    } while (0)

    f32x4 acc[8][4] = {};

#define PHASE(t, mh, kk, STAGE_STMT, WAIT_STMT)                                         \
    do {                                                                                \
        const char* Ah_ = (const char*)&AL[(t) & 1][(kk)][0];                           \
        const char* Bh_ = (const char*)&BL[(t) & 1][(kk)][0];                           \
        half8 a_[4], b_[4];                                                             \
        _Pragma("unroll") for (int mi = 0; mi < 4; ++mi) {                              \
            int r_ = wr * 128 + (mh)*64 + mi * 16 + lr;                                 \
            a_[mi] = *(const half8*)(Ah_ + r_ * 64 + ((q * 16) ^ ((r_ & 3) << 4)));     \
        }                                                                               \
        _Pragma("unroll") for (int ni = 0; ni < 4; ++ni) {                              \
            int r_ = wc4 * 64 + ni * 16 + lr;                                           \
            b_[ni] = *(const half8*)(Bh_ + r_ * 64 + ((q * 16) ^ ((r_ & 3) << 4)));     \
        }                                                                               \
        STAGE_STMT;                                                                     \
        asm volatile("" ::: "memory");                                                  \
        __builtin_amdgcn_s_barrier();                                                   \
        asm volatile("" ::: "memory");                                                  \
        __builtin_amdgcn_s_setprio(1);                                                  \
        _Pragma("unroll") for (int mi = 0; mi < 4; ++mi)                                \
            _Pragma("unroll") for (int ni = 0; ni < 4; ++ni)                            \
                acc[(mh)*4 + mi][ni] = __builtin_amdgcn_mfma_f32_16x16x32_f16(          \
                    a_[mi], b_[ni], acc[(mh)*4 + mi][ni], 0, 0, 0);                     \
        __builtin_amdgcn_s_setprio(0);                                                  \
        WAIT_STMT;                                                                      \
        asm volatile("" ::: "memory");                                                  \
        __builtin_amdgcn_s_barrier();                                                   \
        asm volatile("" ::: "memory");                                                  \
    } while (0)

#define VM4 asm volatile("s_waitcnt vmcnt(4)" ::: "memory")
#define VM0 asm volatile("s_waitcnt vmcnt(0)" ::: "memory")

    // prologue: T0 full (8 loads/wave) + T1 k0-halves (4) -> wait oldest 8
    ST_A(0, 0); ST_B(0, 0); ST_A(0, 1); ST_B(0, 1);
    ST_A(1, 0); ST_B(1, 0);
    VM4;
    asm volatile("" ::: "memory");
    __builtin_amdgcn_s_barrier();
    asm volatile("" ::: "memory");

    for (int it = 0; it < 4; ++it) {
        const int T = 2 * it, U = T + 1;
        const bool lastit = (it == 3);
        PHASE(T, 0, 0, { ST_A(U, 1); }, {});
        PHASE(T, 1, 0, { ST_B(U, 1); }, {});
        PHASE(T, 0, 1, { if (!lastit) ST_A(T + 2, 0); }, {});
        PHASE(T, 1, 1, { if (!lastit) ST_B(T + 2, 0); }, { if (lastit) VM0; else VM4; });
        PHASE(U, 0, 0, { if (!lastit) ST_A(T + 2, 1); }, {});
        PHASE(U, 1, 0, { if (!lastit) ST_B(T + 2, 1); }, {});
        PHASE(U, 0, 1, { if (!lastit) ST_A(T + 3, 0); }, {});
        PHASE(U, 1, 1, { if (!lastit) ST_B(T + 3, 0); }, { if (!lastit) VM4; });
    }

    // epilogue: tanh + bias, reduce the wave's 128 l-rows per h, atomicAdd
#pragma unroll
    for (int ni = 0; ni < 4; ++ni) {
        const int h = h0 + wc4 * 64 + ni * 16 + lr;
        const float bsv = bias[h];
        float ssum = 0.f;
#pragma unroll
        for (int mI = 0; mI < 8; ++mI)
#pragma unroll
            for (int r4 = 0; r4 < 4; ++r4)
                ssum += fast_tanh(acc[mI][ni][r4] + bsv);
        ssum += __shfl_xor(ssum, 16);
        ssum += __shfl_xor(ssum, 32);
        if (q == 0) atomicAdd(&out[bb * H_ + h], ssum * (0.5f / (float)L_));
    }
#undef PHASE
#undef ST_A
#undef ST_B
#undef VM4
#undef VM0
}

extern "C" void kernel_launch(void* const* d_in, const int* in_sizes, int n_in,
                              void* d_out, int out_size, void* d_ws, size_t ws_size,
                              hipStream_t stream) {
    const float* I = (const float*)d_in[0];
    const float* Jm = (const float*)d_in[1];
    const float* W = (const float*)d_in[2];
    const float* bias = (const float*)d_in[3];
    float* out = (float*)d_out;

    const size_t BLD = (size_t)B_ * L_ * D_;
    const size_t BLL = (size_t)B_ * L_ * L_;

    char* p = (char*)d_ws;
    auto give = [&](size_t bytes) {
        char* r = p;
        p += (bytes + 255) & ~(size_t)255;
        return r;
    };
    u16* Ih = (u16*)give(BLD * 2);
    u16* Jh = (u16*)give(BLD * 2);
    u16* IhT = (u16*)give(BLD * 2);
    u16* JhT = (u16*)give(BLD * 2);
    u16* WT = (u16*)give((size_t)D_ * H_ * 2);
    u16* P_un = (u16*)give(BLL * 2);
    u16* P_unT = (u16*)give(BLL * 2);
    float* rtmax = (float*)give((size_t)B_ * L_ * 8 * 4);
    float* rtsum = (float*)give((size_t)B_ * L_ * 8 * 4);
    float* ctmax = (float*)give((size_t)B_ * L_ * 8 * 4);
    float* ctsum = (float*)give((size_t)B_ * L_ * 8 * 4);
    u16* Xall = (u16*)give(2 * BLD * 2);

    cvt_all<<<dim3(8, 8, 65), 256, 0, stream>>>(I, Jm, W, Ih, IhT, Jh, JhT, WT, out);
    score_mfma<<<512, 256, 0, stream>>>(Ih, Jh, P_un, P_unT, rtmax, rtsum, ctmax, ctsum);
    absdiff_8ph<<<256, 512, 0, stream>>>(P_un, P_unT, rtmax, rtsum, ctmax, ctsum,
                                         JhT, IhT, Ih, Jh, Xall);
    agg_8ph<<<256, 512, 0, stream>>>(Xall, WT, bias, out);
}